// Round 7
// baseline (255.627 us; speedup 1.0000x reference)
//
#include <hip/hip_runtime.h>
#include <hip/hip_bf16.h>

typedef short s8v __attribute__((ext_vector_type(8)));   // 8 bf16 = 16B (4 VGPR)
typedef float f4v __attribute__((ext_vector_type(4)));   // MFMA accum

#define MFMA_BF16(a, b, c) __builtin_amdgcn_mfma_f32_16x16x32_bf16((a), (b), (c), 0, 0, 0)

// async global->LDS, 16B per lane; LDS dest = wave-uniform base + lane*16
#define GLDS16(g, l) __builtin_amdgcn_global_load_lds( \
    (const __attribute__((address_space(1))) void*)(g), \
    (__attribute__((address_space(3))) void*)(l), 16, 0, 0)

__device__ __forceinline__ short f2bf(float f) {
  __hip_bfloat16 h = __float2bfloat16(f);
  return *reinterpret_cast<short*>(&h);
}
__device__ __forceinline__ float bf2f(short s) {
  __hip_bfloat16 h;
  *reinterpret_cast<short*>(&h) = s;
  return __bfloat162float(h);
}

// ---------------- fp32 -> bf16 conversion ----------------
__global__ __launch_bounds__(256) void cvt_kernel(const float* __restrict__ in,
                                                  short* __restrict__ out, int n8) {
  int i = blockIdx.x * 256 + threadIdx.x;
  if (i >= n8) return;
  const float* p = in + (size_t)i * 8;
  float4 a = *(const float4*)p;
  float4 b = *(const float4*)(p + 4);
  s8v o;
  o[0] = f2bf(a.x); o[1] = f2bf(a.y); o[2] = f2bf(a.z); o[3] = f2bf(a.w);
  o[4] = f2bf(b.x); o[5] = f2bf(b.y); o[6] = f2bf(b.z); o[7] = f2bf(b.w);
  *(s8v*)(out + (size_t)i * 8) = o;
}

// ------- 256x256 tile GEMM core, BK=64, 8 waves (2Mx4N), counted vmcnt -------
// A row-major [M][ASTR] over K; B row-major [N][BSTR] over K (B^T layout).
// LDS ring: 2 K-tile buffers x {A,B} x {half0,half1} x [128 rows][64 shorts].
// Depth-2 prefetch: at tile t, vmcnt(8) keeps t+1's 8 loads in flight (T4);
// stage(t+2) overwrites buf after lgkmcnt(0)+barrier proves all reads done.
// XOR swizzle (row&7)<<4 on per-lane global source AND ds_read addr (rule 21).
template<int KT, int ASTR, int BSTR>
__device__ __forceinline__ void mm256_core(const short* __restrict__ Ab,
                                           const short* __restrict__ Bb,
                                           short* lds, f4v (&acc)[8][4]) {
  const int t = threadIdx.x;
  const int lane = t & 63, wv = t >> 6;
  const int wm = wv >> 2, wn = wv & 3;      // wave tile: rows wm*128, cols wn*64
  const int lr = lane & 15, lg = lane >> 4;

  const int srow = t >> 3;                  // staging row 0..63 (+64 for j=1)
  const int scol = (t & 7) * 16;            // byte in row
  const int sswz = scol ^ ((srow & 7) << 4);

  auto stage = [&](int tt) {
    short* buf = lds + (tt & 1) * 32768;
    #pragma unroll
    for (int m = 0; m < 2; ++m) {           // 0 = A, 1 = B
      const short* src = m ? Bb : Ab;
      const int str = m ? BSTR : ASTR;
      #pragma unroll
      for (int h = 0; h < 2; ++h)
        #pragma unroll
        for (int j = 0; j < 2; ++j) {
          int row = srow + j * 64;
          GLDS16((const char*)(src + (size_t)(h * 128 + row) * str + tt * 64) + sswz,
                 (char*)(buf + (m * 2 + h) * 8192) + row * 128 + scol);
        }
    }
  };

  stage(0);
  stage(1);

  const int bhalf = wn >> 1;
  const int brow0 = (wn & 1) * 64;

  for (int tt = 0; tt < KT; ++tt) {
    if (tt + 1 < KT) asm volatile("s_waitcnt vmcnt(8)" ::: "memory");
    else             asm volatile("s_waitcnt vmcnt(0)" ::: "memory");
    __builtin_amdgcn_s_barrier();
    const char* bufA = (const char*)(lds + (tt & 1) * 32768 + wm * 8192);
    const char* bufB = (const char*)(lds + (tt & 1) * 32768 + (2 + bhalf) * 8192);
    #pragma unroll
    for (int kk = 0; kk < 2; ++kk) {
      s8v af[8], bfr[4];
      #pragma unroll
      for (int mf = 0; mf < 8; ++mf)
        af[mf] = *(const s8v*)(bufA + (mf * 16 + lr) * 128 +
                               ((kk * 64 + lg * 16) ^ ((lr & 7) << 4)));
      #pragma unroll
      for (int nf = 0; nf < 4; ++nf)
        bfr[nf] = *(const s8v*)(bufB + (brow0 + nf * 16 + lr) * 128 +
                                ((kk * 64 + lg * 16) ^ ((lr & 7) << 4)));
      if (kk == 1) {
        // all this wave's reads of buf issued+counted; prove done, then let
        // the whole block overwrite this buffer with tile t+2.
        asm volatile("s_waitcnt lgkmcnt(0)" ::: "memory");
        __builtin_amdgcn_s_barrier();
        if (tt + 2 < KT) stage(tt + 2);
      }
      __builtin_amdgcn_s_setprio(1);
      #pragma unroll
      for (int mf = 0; mf < 8; ++mf)
        #pragma unroll
        for (int nf = 0; nf < 4; ++nf)
          acc[mf][nf] = MFMA_BF16(af[mf], bfr[nf], acc[mf][nf]);
      __builtin_amdgcn_s_setprio(0);
    }
  }
}

// ---------------- projections: y = x @ W^T + b ----------------
__global__ __launch_bounds__(512, 2) void proj_kernel(
    const short* __restrict__ xb, const short* __restrict__ wb,
    const float* __restrict__ bq, const float* __restrict__ bk, const float* __restrict__ bv,
    short* __restrict__ qo, short* __restrict__ ko, short* __restrict__ vo) {
  const int bx = blockIdx.x;
  const int L = (bx & 7) * 96 + (bx >> 3);    // bijective XCD swizzle (768 = 8*96)
  const int cb = L & 1, rbm = L >> 1;         // 2 col-blocks of 256
  const int mat = rbm >> 7, rb = rbm & 127;   // 128 row-blocks per matrix
  const int R0 = rb * 256, C0 = cb * 256;
  const float* bias = (mat == 0) ? bq : (mat == 1) ? bk : bv;
  short* out = (mat == 0) ? qo : (mat == 1) ? ko : vo;

  __shared__ short lds[65536];
  f4v acc[8][4];
  #pragma unroll
  for (int i = 0; i < 8; i++)
    #pragma unroll
    for (int j = 0; j < 4; j++) acc[i][j] = (f4v){0.f, 0.f, 0.f, 0.f};

  mm256_core<8, 512, 512>(xb + (size_t)R0 * 512,
                          wb + (size_t)mat * 512 * 512 + (size_t)C0 * 512, lds, acc);

  const int lane = threadIdx.x & 63, wv = threadIdx.x >> 6;
  const int wm = wv >> 2, wn = wv & 3;
  const int lr = lane & 15, lg = lane >> 4;
  #pragma unroll
  for (int nf = 0; nf < 4; ++nf) {
    int col = C0 + wn * 64 + nf * 16 + lr;
    float bb = bias[col];
    #pragma unroll
    for (int mf = 0; mf < 8; ++mf)
      #pragma unroll
      for (int i = 0; i < 4; i++) {
        int row = R0 + wm * 128 + mf * 16 + lg * 4 + i;
        out[(size_t)row * 512 + col] = f2bf(acc[mf][nf][i] + bb);
      }
  }
}

// ---------------- v (B,C,N) -> v_t (B,N,C) ----------------
__global__ __launch_bounds__(256) void transpose_kernel(const short* __restrict__ v,
                                                        short* __restrict__ vt) {
  const int nb = blockIdx.x;
  const int cbk = blockIdx.y;
  const int b = blockIdx.z;
  __shared__ short tile[64 * 72];
  const int t = threadIdx.x;
  const int r = t >> 2, qd = t & 3;
  const short* src = v + (size_t)(b * 1024 + cbk * 64 + r) * 512 + nb * 64 + qd * 16;
  s8v v0 = *(const s8v*)src;
  s8v v1 = *(const s8v*)(src + 8);
  *(s8v*)&tile[r * 72 + qd * 16] = v0;
  *(s8v*)&tile[r * 72 + qd * 16 + 8] = v1;
  __syncthreads();
  s8v o0, o1;
  #pragma unroll
  for (int j = 0; j < 8; j++) o0[j] = tile[(qd * 16 + j) * 72 + r];
  #pragma unroll
  for (int j = 0; j < 8; j++) o1[j] = tile[(qd * 16 + 8 + j) * 72 + r];
  short* dst = vt + (size_t)(b * 512 + nb * 64 + r) * 1024 + cbk * 64 + qd * 16;
  *(s8v*)dst = o0;
  *(s8v*)(dst + 8) = o1;
}

// ---------------- E = Q @ K^T per batch ----------------
__global__ __launch_bounds__(512, 2) void qk_kernel(const short* __restrict__ qb,
                                                    const short* __restrict__ kb,
                                                    short* __restrict__ eb) {
  const int bx = blockIdx.x;
  const int L = (bx & 7) * 64 + (bx >> 3);    // 512 = 8*64
  const int cb = L & 3, rbb = L >> 2;
  const int rb = rbb & 3, b = rbb >> 2;
  const int R0 = rb * 256, C0 = cb * 256;

  __shared__ short lds[65536];
  f4v acc[8][4];
  #pragma unroll
  for (int i = 0; i < 8; i++)
    #pragma unroll
    for (int j = 0; j < 4; j++) acc[i][j] = (f4v){0.f, 0.f, 0.f, 0.f};

  mm256_core<8, 512, 512>(qb + (size_t)(b * 1024 + R0) * 512,
                          kb + (size_t)(b * 1024 + C0) * 512, lds, acc);

  const int lane = threadIdx.x & 63, wv = threadIdx.x >> 6;
  const int wm = wv >> 2, wn = wv & 3;
  const int lr = lane & 15, lg = lane >> 4;
  #pragma unroll
  for (int nf = 0; nf < 4; ++nf) {
    int col = C0 + wn * 64 + nf * 16 + lr;
    #pragma unroll
    for (int mf = 0; mf < 8; ++mf)
      #pragma unroll
      for (int i = 0; i < 4; i++) {
        int row = R0 + wm * 128 + mf * 16 + lg * 4 + i;
        eb[(size_t)(b * 1024 + row) * 1024 + col] = f2bf(acc[mf][nf][i]);
      }
  }
}

// ---------------- in-place row softmax (rows of 1024 bf16) ----------------
__global__ __launch_bounds__(256) void softmax_kernel(short* __restrict__ eb) {
  const int row = blockIdx.x * 4 + (threadIdx.x >> 6);
  const int lane = threadIdx.x & 63;
  short* p = eb + (size_t)row * 1024 + lane * 16;
  s8v a = *(const s8v*)p;
  s8v bvv = *(const s8v*)(p + 8);
  float v[16];
  #pragma unroll
  for (int j = 0; j < 8; j++) { v[j] = bf2f(a[j]); v[8 + j] = bf2f(bvv[j]); }
  float m = v[0];
  #pragma unroll
  for (int j = 1; j < 16; j++) m = fmaxf(m, v[j]);
  #pragma unroll
  for (int s = 1; s <= 32; s <<= 1) m = fmaxf(m, __shfl_xor(m, s));
  float l = 0.f;
  #pragma unroll
  for (int j = 0; j < 16; j++) { v[j] = __expf(v[j] - m); l += v[j]; }
  #pragma unroll
  for (int s = 1; s <= 32; s <<= 1) l += __shfl_xor(l, s);
  const float inv = 1.0f / l;
  s8v o0, o1;
  #pragma unroll
  for (int j = 0; j < 8; j++) { o0[j] = f2bf(v[j] * inv); o1[j] = f2bf(v[8 + j] * inv); }
  *(s8v*)p = o0;
  *(s8v*)(p + 8) = o1;
}

// ---------------- out = beta * (P @ V) + v ----------------
__global__ __launch_bounds__(512, 2) void pv_kernel(const short* __restrict__ eb,
                                                    const short* __restrict__ vt,
                                                    const short* __restrict__ vb,
                                                    const float* __restrict__ beta_p,
                                                    float* __restrict__ outp) {
  const int bx = blockIdx.x;
  const int L = (bx & 7) * 32 + (bx >> 3);    // 256 = 8*32
  const int cb = L & 1, rbb = L >> 1;
  const int rb = rbb & 3, b = rbb >> 2;
  const int R0 = rb * 256, C0 = cb * 256;

  __shared__ short lds[65536];
  f4v acc[8][4];
  #pragma unroll
  for (int i = 0; i < 8; i++)
    #pragma unroll
    for (int j = 0; j < 4; j++) acc[i][j] = (f4v){0.f, 0.f, 0.f, 0.f};

  mm256_core<16, 1024, 1024>(eb + (size_t)(b * 1024 + R0) * 1024,
                             vt + (size_t)(b * 512 + C0) * 1024, lds, acc);

  const float beta = beta_p[0];
  const int lane = threadIdx.x & 63, wv = threadIdx.x >> 6;
  const int wm = wv >> 2, wn = wv & 3;
  const int lr = lane & 15, lg = lane >> 4;
  #pragma unroll
  for (int nf = 0; nf < 4; ++nf) {
    int col = C0 + wn * 64 + nf * 16 + lr;
    #pragma unroll
    for (int mf = 0; mf < 8; ++mf)
      #pragma unroll
      for (int i = 0; i < 4; i++) {
        int row = R0 + wm * 128 + mf * 16 + lg * 4 + i;
        float val = beta * acc[mf][nf][i] +
                    bf2f(vb[(size_t)(b * 1024 + row) * 512 + col]);
        outp[(size_t)(b * 1024 + row) * 512 + col] = val;
      }
  }
}

extern "C" void kernel_launch(void* const* d_in, const int* in_sizes, int n_in,
                              void* d_out, int out_size, void* d_ws, size_t ws_size,
                              hipStream_t stream) {
  (void)in_sizes; (void)n_in; (void)out_size; (void)ws_size;
  const float* x = (const float*)d_in[0];
  const float* Wq = (const float*)d_in[1];
  const float* bq = (const float*)d_in[2];
  const float* Wk = (const float*)d_in[3];
  const float* bk = (const float*)d_in[4];
  const float* Wv = (const float*)d_in[5];
  const float* bv = (const float*)d_in[6];
  const float* beta = (const float*)d_in[7];
  float* out = (float*)d_out;

  char* ws = (char*)d_ws;
  short* xb = (short*)(ws);                  // 32MB, reused as v_t after proj
  short* wb = (short*)(ws + 33554432);       // 1.5MB
  short* qb = (short*)(ws + 35127296);       // 32MB
  short* kb = (short*)(ws + 68681728);       // 32MB
  short* vb = (short*)(ws + 102236160);      // 32MB
  short* eb = (short*)(ws + 135790592);      // 64MB (E, then P in-place)
  short* vt = xb;

  cvt_kernel<<<8192, 256, 0, stream>>>(x, xb, 2097152);
  cvt_kernel<<<128, 256, 0, stream>>>(Wq, wb, 32768);
  cvt_kernel<<<128, 256, 0, stream>>>(Wk, wb + 262144, 32768);
  cvt_kernel<<<128, 256, 0, stream>>>(Wv, wb + 524288, 32768);
  proj_kernel<<<768, 512, 0, stream>>>(xb, wb, bq, bk, bv, qb, kb, vb);
  transpose_kernel<<<dim3(8, 16, 32), 256, 0, stream>>>(vb, vt);
  qk_kernel<<<512, 512, 0, stream>>>(qb, kb, eb);
  softmax_kernel<<<8192, 256, 0, stream>>>(eb);
  pv_kernel<<<256, 512, 0, stream>>>(eb, vt, vb, beta, out);
}

// Round 8
// 220.173 us; speedup vs baseline: 1.1610x; 1.1610x over previous
//
#include <hip/hip_runtime.h>
#include <hip/hip_bf16.h>

typedef short s8v __attribute__((ext_vector_type(8)));   // 8 bf16 = 16B (4 VGPR)
typedef float f4v __attribute__((ext_vector_type(4)));   // MFMA accum

#define MFMA_BF16(a, b, c) __builtin_amdgcn_mfma_f32_16x16x32_bf16((a), (b), (c), 0, 0, 0)

// async global->LDS, 16B per lane; LDS dest = wave-uniform base + lane*16
#define GLDS16(g, l) __builtin_amdgcn_global_load_lds( \
    (const __attribute__((address_space(1))) void*)(g), \
    (__attribute__((address_space(3))) void*)(l), 16, 0, 0)

__device__ __forceinline__ short f2bf(float f) {
  __hip_bfloat16 h = __float2bfloat16(f);
  return *reinterpret_cast<short*>(&h);
}
__device__ __forceinline__ float bf2f(short s) {
  __hip_bfloat16 h;
  *reinterpret_cast<short*>(&h) = s;
  return __bfloat162float(h);
}

// ---------------- fp32 -> bf16 conversion ----------------
__global__ __launch_bounds__(256) void cvt_kernel(const float* __restrict__ in,
                                                  short* __restrict__ out, int n8) {
  int i = blockIdx.x * 256 + threadIdx.x;
  if (i >= n8) return;
  const float* p = in + (size_t)i * 8;
  float4 a = *(const float4*)p;
  float4 b = *(const float4*)(p + 4);
  s8v o;
  o[0] = f2bf(a.x); o[1] = f2bf(a.y); o[2] = f2bf(a.z); o[3] = f2bf(a.w);
  o[4] = f2bf(b.x); o[5] = f2bf(b.y); o[6] = f2bf(b.z); o[7] = f2bf(b.w);
  *(s8v*)(out + (size_t)i * 8) = o;
}

// ------- 128x128 GEMM core, BK=64, 4 waves, 2-buffer ring, counted vmcnt ----
// A row-major [M][ASTR] over K; B row-major [N][BSTR] over K (B^T layout).
// Per K-tile: vmcnt(8) [this tile landed, next tile's 8 loads stay in flight]
// -> barrier -> kk0 frags+MFMA -> kk1 frags -> lgkmcnt(0) -> barrier ->
// stage(t+2) into freed buffer -> kk1 MFMA.  2 blocks/CU (64KB LDS) supply
// cross-block TLP during waits.  XOR swizzle (row&7)<<4 on per-lane global
// source AND ds_read addr (rule 21) -> 0 bank conflicts (verified R5/R6).
template<int KSTEPS, int ASTR, int BSTR>
__device__ __forceinline__ void mm_core(const short* __restrict__ Abase,
                                        const short* __restrict__ Bbase,
                                        short* As0, short* Bs0,
                                        short* As1, short* Bs1,
                                        f4v (&acc)[4][4]) {
  const int t = threadIdx.x;
  const int lane = t & 63, w = t >> 6;
  const int lr = lane & 15, lg = lane >> 4;
  const int wr = (w >> 1) * 64, wc = (w & 1) * 64;
  const int srcc = ((lane & 7) * 16) ^ ((lane >> 3) << 4);  // swizzled src col byte
  const int rstage = w * 32 + (lane >> 3);

  auto stage = [&](short* As, short* Bs, int kt) {
    #pragma unroll
    for (int j = 0; j < 4; ++j)
      GLDS16((const char*)(Abase + (size_t)(rstage + j * 8) * ASTR) + kt * 128 + srcc,
             (char*)As + (w * 32 + j * 8) * 128);
    #pragma unroll
    for (int j = 0; j < 4; ++j)
      GLDS16((const char*)(Bbase + (size_t)(rstage + j * 8) * BSTR) + kt * 128 + srcc,
             (char*)Bs + (w * 32 + j * 8) * 128);
  };

  stage(As0, Bs0, 0);
  if (KSTEPS > 1) stage(As1, Bs1, 1);
  short* Asc = As0; short* Bsc = Bs0;
  short* Asn = As1; short* Bsn = Bs1;

  for (int kt = 0; kt < KSTEPS; ++kt) {
    if (kt + 1 < KSTEPS) asm volatile("s_waitcnt vmcnt(8)" ::: "memory");
    else                 asm volatile("s_waitcnt vmcnt(0)" ::: "memory");
    __builtin_amdgcn_s_barrier();
    #pragma unroll
    for (int kk = 0; kk < 2; ++kk) {
      s8v af[4], bfr[4];
      #pragma unroll
      for (int mf = 0; mf < 4; ++mf)
        af[mf] = *(const s8v*)((const char*)Asc + (wr + mf * 16 + lr) * 128 +
                               ((kk * 64 + lg * 16) ^ ((lr & 7) << 4)));
      #pragma unroll
      for (int nf = 0; nf < 4; ++nf)
        bfr[nf] = *(const s8v*)((const char*)Bsc + (wc + nf * 16 + lr) * 128 +
                                ((kk * 64 + lg * 16) ^ ((lr & 7) << 4)));
      if (kk == 1) {
        // this wave's reads of the current buffer are all issued; prove they
        // completed, then the whole block may overwrite it with tile t+2.
        asm volatile("s_waitcnt lgkmcnt(0)" ::: "memory");
        __builtin_amdgcn_s_barrier();
        if (kt + 2 < KSTEPS) stage(Asc, Bsc, kt + 2);
      }
      __builtin_amdgcn_s_setprio(1);
      #pragma unroll
      for (int mf = 0; mf < 4; ++mf)
        #pragma unroll
        for (int nf = 0; nf < 4; ++nf)
          acc[mf][nf] = MFMA_BF16(af[mf], bfr[nf], acc[mf][nf]);
      __builtin_amdgcn_s_setprio(0);
    }
    short* ta = Asc; Asc = Asn; Asn = ta;
    short* tb = Bsc; Bsc = Bsn; Bsn = tb;
  }
}

// ---------------- projections: y = x @ W^T + b ----------------
__global__ __launch_bounds__(256) void proj_kernel(
    const short* __restrict__ xb, const short* __restrict__ wb,
    const float* __restrict__ bq, const float* __restrict__ bk, const float* __restrict__ bv,
    short* __restrict__ qo, short* __restrict__ ko, short* __restrict__ vo) {
  const int bx = blockIdx.x;
  const int L = (bx & 7) * 384 + (bx >> 3);   // bijective XCD swizzle (3072 = 8*384)
  const int cb = L & 3, rb = (L >> 2) & 255, mat = L >> 10;
  const int R0 = rb * 128, C0 = cb * 128;
  const float* bias = (mat == 0) ? bq : (mat == 1) ? bk : bv;
  short* out = (mat == 0) ? qo : (mat == 1) ? ko : vo;

  __shared__ short As0[8192], Bs0[8192], As1[8192], Bs1[8192];
  f4v acc[4][4];
  #pragma unroll
  for (int i = 0; i < 4; i++)
    #pragma unroll
    for (int j = 0; j < 4; j++) acc[i][j] = (f4v){0.f, 0.f, 0.f, 0.f};

  mm_core<8, 512, 512>(xb + (size_t)R0 * 512,
                       wb + (size_t)mat * 512 * 512 + (size_t)C0 * 512,
                       As0, Bs0, As1, Bs1, acc);

  const int lane = threadIdx.x & 63, w = threadIdx.x >> 6;
  const int lr = lane & 15, lg = lane >> 4;
  const int wr = (w >> 1) * 64, wc = (w & 1) * 64;
  #pragma unroll
  for (int nf = 0; nf < 4; ++nf) {
    int col = C0 + wc + nf * 16 + lr;
    float bb = bias[col];
    #pragma unroll
    for (int mf = 0; mf < 4; ++mf)
      #pragma unroll
      for (int i = 0; i < 4; i++) {
        int row = R0 + wr + mf * 16 + lg * 4 + i;
        out[(size_t)row * 512 + col] = f2bf(acc[mf][nf][i] + bb);
      }
  }
}

// ---------------- v (B,C,N) -> v_t (B,N,C) ----------------
__global__ __launch_bounds__(256) void transpose_kernel(const short* __restrict__ v,
                                                        short* __restrict__ vt) {
  const int nb = blockIdx.x;
  const int cbk = blockIdx.y;
  const int b = blockIdx.z;
  __shared__ short tile[64 * 72];
  const int t = threadIdx.x;
  const int r = t >> 2, qd = t & 3;
  const short* src = v + (size_t)(b * 1024 + cbk * 64 + r) * 512 + nb * 64 + qd * 16;
  s8v v0 = *(const s8v*)src;
  s8v v1 = *(const s8v*)(src + 8);
  *(s8v*)&tile[r * 72 + qd * 16] = v0;
  *(s8v*)&tile[r * 72 + qd * 16 + 8] = v1;
  __syncthreads();
  s8v o0, o1;
  #pragma unroll
  for (int j = 0; j < 8; j++) o0[j] = tile[(qd * 16 + j) * 72 + r];
  #pragma unroll
  for (int j = 0; j < 8; j++) o1[j] = tile[(qd * 16 + 8 + j) * 72 + r];
  short* dst = vt + (size_t)(b * 512 + nb * 64 + r) * 1024 + cbk * 64 + qd * 16;
  *(s8v*)dst = o0;
  *(s8v*)(dst + 8) = o1;
}

// ---------------- E = Q @ K^T per batch ----------------
__global__ __launch_bounds__(256) void qk_kernel(const short* __restrict__ qb,
                                                 const short* __restrict__ kb,
                                                 short* __restrict__ eb) {
  const int bx = blockIdx.x;
  const int L = (bx & 7) * 256 + (bx >> 3);   // 2048 = 8*256
  const int rb = L & 7, cb = (L >> 3) & 7, b = L >> 6;
  const int R0 = rb * 128, C0 = cb * 128;

  __shared__ short As0[8192], Bs0[8192], As1[8192], Bs1[8192];
  f4v acc[4][4];
  #pragma unroll
  for (int i = 0; i < 4; i++)
    #pragma unroll
    for (int j = 0; j < 4; j++) acc[i][j] = (f4v){0.f, 0.f, 0.f, 0.f};

  mm_core<8, 512, 512>(qb + (size_t)(b * 1024 + R0) * 512,
                       kb + (size_t)(b * 1024 + C0) * 512,
                       As0, Bs0, As1, Bs1, acc);

  const int lane = threadIdx.x & 63, w = threadIdx.x >> 6;
  const int lr = lane & 15, lg = lane >> 4;
  const int wr = (w >> 1) * 64, wc = (w & 1) * 64;
  #pragma unroll
  for (int nf = 0; nf < 4; ++nf) {
    int col = C0 + wc + nf * 16 + lr;
    #pragma unroll
    for (int mf = 0; mf < 4; ++mf)
      #pragma unroll
      for (int i = 0; i < 4; i++) {
        int row = R0 + wr + mf * 16 + lg * 4 + i;
        eb[(size_t)(b * 1024 + row) * 1024 + col] = f2bf(acc[mf][nf][i]);
      }
  }
}

// ---------------- in-place row softmax (rows of 1024 bf16) ----------------
__global__ __launch_bounds__(256) void softmax_kernel(short* __restrict__ eb) {
  const int row = blockIdx.x * 4 + (threadIdx.x >> 6);
  const int lane = threadIdx.x & 63;
  short* p = eb + (size_t)row * 1024 + lane * 16;
  s8v a = *(const s8v*)p;
  s8v bvv = *(const s8v*)(p + 8);
  float v[16];
  #pragma unroll
  for (int j = 0; j < 8; j++) { v[j] = bf2f(a[j]); v[8 + j] = bf2f(bvv[j]); }
  float m = v[0];
  #pragma unroll
  for (int j = 1; j < 16; j++) m = fmaxf(m, v[j]);
  #pragma unroll
  for (int s = 1; s <= 32; s <<= 1) m = fmaxf(m, __shfl_xor(m, s));
  float l = 0.f;
  #pragma unroll
  for (int j = 0; j < 16; j++) { v[j] = __expf(v[j] - m); l += v[j]; }
  #pragma unroll
  for (int s = 1; s <= 32; s <<= 1) l += __shfl_xor(l, s);
  const float inv = 1.0f / l;
  s8v o0, o1;
  #pragma unroll
  for (int j = 0; j < 8; j++) { o0[j] = f2bf(v[j] * inv); o1[j] = f2bf(v[8 + j] * inv); }
  *(s8v*)p = o0;
  *(s8v*)(p + 8) = o1;
}

// ---------------- out = beta * (P @ V) + v ----------------
__global__ __launch_bounds__(256) void pv_kernel(const short* __restrict__ eb,
                                                 const short* __restrict__ vt,
                                                 const short* __restrict__ vb,
                                                 const float* __restrict__ beta_p,
                                                 float* __restrict__ outp) {
  const int bx = blockIdx.x;
  const int L = (bx & 7) * 128 + (bx >> 3);   // 1024 = 8*128
  const int cb = L & 3, rb = (L >> 2) & 7, b = L >> 5;
  const int R0 = rb * 128, C0 = cb * 128;

  __shared__ short As0[8192], Bs0[8192], As1[8192], Bs1[8192];
  f4v acc[4][4];
  #pragma unroll
  for (int i = 0; i < 4; i++)
    #pragma unroll
    for (int j = 0; j < 4; j++) acc[i][j] = (f4v){0.f, 0.f, 0.f, 0.f};

  mm_core<16, 1024, 1024>(eb + (size_t)(b * 1024 + R0) * 1024,
                          vt + (size_t)(b * 512 + C0) * 1024,
                          As0, Bs0, As1, Bs1, acc);

  const float beta = beta_p[0];
  const int lane = threadIdx.x & 63, w = threadIdx.x >> 6;
  const int lr = lane & 15, lg = lane >> 4;
  const int wr = (w >> 1) * 64, wc = (w & 1) * 64;
  #pragma unroll
  for (int nf = 0; nf < 4; ++nf) {
    int col = C0 + wc + nf * 16 + lr;
    #pragma unroll
    for (int mf = 0; mf < 4; ++mf)
      #pragma unroll
      for (int i = 0; i < 4; i++) {
        int row = R0 + wr + mf * 16 + lg * 4 + i;
        float val = beta * acc[mf][nf][i] +
                    bf2f(vb[(size_t)(b * 1024 + row) * 512 + col]);
        outp[(size_t)(b * 1024 + row) * 512 + col] = val;
      }
  }
}

extern "C" void kernel_launch(void* const* d_in, const int* in_sizes, int n_in,
                              void* d_out, int out_size, void* d_ws, size_t ws_size,
                              hipStream_t stream) {
  (void)in_sizes; (void)n_in; (void)out_size; (void)ws_size;
  const float* x = (const float*)d_in[0];
  const float* Wq = (const float*)d_in[1];
  const float* bq = (const float*)d_in[2];
  const float* Wk = (const float*)d_in[3];
  const float* bk = (const float*)d_in[4];
  const float* Wv = (const float*)d_in[5];
  const float* bv = (const float*)d_in[6];
  const float* beta = (const float*)d_in[7];
  float* out = (float*)d_out;

  char* ws = (char*)d_ws;
  short* xb = (short*)(ws);                  // 32MB, reused as v_t after proj
  short* wb = (short*)(ws + 33554432);       // 1.5MB
  short* qb = (short*)(ws + 35127296);       // 32MB
  short* kb = (short*)(ws + 68681728);       // 32MB
  short* vb = (short*)(ws + 102236160);      // 32MB
  short* eb = (short*)(ws + 135790592);      // 64MB (E, then P in-place)
  short* vt = xb;

  cvt_kernel<<<8192, 256, 0, stream>>>(x, xb, 2097152);
  cvt_kernel<<<128, 256, 0, stream>>>(Wq, wb, 32768);
  cvt_kernel<<<128, 256, 0, stream>>>(Wk, wb + 262144, 32768);
  cvt_kernel<<<128, 256, 0, stream>>>(Wv, wb + 524288, 32768);
  proj_kernel<<<3072, 256, 0, stream>>>(xb, wb, bq, bk, bv, qb, kb, vb);
  transpose_kernel<<<dim3(8, 16, 32), 256, 0, stream>>>(vb, vt);
  qk_kernel<<<2048, 256, 0, stream>>>(qb, kb, eb);
  softmax_kernel<<<8192, 256, 0, stream>>>(eb);
  pv_kernel<<<1024, 256, 0, stream>>>(eb, vt, vb, beta, out);
}